// Round 13
// baseline (13844.980 us; speedup 1.0000x reference)
//
#include <hip/hip_runtime.h>
#include <hip/hip_bf16.h>
#include <math.h>

#define T_STEPS 4096
#define IN_DIM  512
#define HID     2048
#define LEAK    0.3f

// ---------------------------------------------------------------------------
// Phase 1: P = U @ Win^T + bias, written directly into d_out (T x HID, f32)
// ---------------------------------------------------------------------------
#define GBM 64
#define GBN 64
#define GBK 32

__global__ __launch_bounds__(256) void gemm_p(const float* __restrict__ U,
                                              const float* __restrict__ Win,
                                              const float* __restrict__ bias,
                                              float* __restrict__ P) {
  __shared__ float As[GBM][GBK + 1];
  __shared__ float Bs[GBN][GBK + 1];
  const int bm = blockIdx.x, bn = blockIdx.y;
  const int tid = threadIdx.x;
  const int tx = tid & 15, ty = tid >> 4;

  float acc[4][4];
#pragma unroll
  for (int m = 0; m < 4; ++m)
#pragma unroll
    for (int n = 0; n < 4; ++n) acc[m][n] = 0.f;

  const float* Ub = U + (size_t)bm * GBM * IN_DIM;
  const float* Wb = Win + (size_t)bn * GBN * IN_DIM;

  for (int k0 = 0; k0 < IN_DIM; k0 += GBK) {
#pragma unroll
    for (int v = 0; v < 2; ++v) {
      const int f4 = v * 256 + tid;
      const int row = f4 >> 3;
      const int c4 = (f4 & 7) << 2;
      const float4 a = *(const float4*)(Ub + (size_t)row * IN_DIM + k0 + c4);
      As[row][c4 + 0] = a.x; As[row][c4 + 1] = a.y;
      As[row][c4 + 2] = a.z; As[row][c4 + 3] = a.w;
      const float4 b = *(const float4*)(Wb + (size_t)row * IN_DIM + k0 + c4);
      Bs[row][c4 + 0] = b.x; Bs[row][c4 + 1] = b.y;
      Bs[row][c4 + 2] = b.z; Bs[row][c4 + 3] = b.w;
    }
    __syncthreads();
#pragma unroll 8
    for (int k = 0; k < GBK; ++k) {
      float a[4], b[4];
#pragma unroll
      for (int m = 0; m < 4; ++m) a[m] = As[ty * 4 + m][k];
#pragma unroll
      for (int n = 0; n < 4; ++n) b[n] = Bs[tx * 4 + n][k];
#pragma unroll
      for (int m = 0; m < 4; ++m)
#pragma unroll
        for (int n = 0; n < 4; ++n)
          acc[m][n] = fmaf(a[m], b[n], acc[m][n]);
    }
    __syncthreads();
  }

#pragma unroll
  for (int m = 0; m < 4; ++m) {
    const int gr = bm * GBM + ty * 4 + m;
#pragma unroll
    for (int n = 0; n < 4; ++n) {
      const int gc = bn * GBN + tx * 4 + n;
      P[(size_t)gr * HID + gc] = acc[m][n] + bias[gc];
    }
  }
}

// ---------------------------------------------------------------------------
// Phase 2: persistent recurrence, tagged-word exchange, two-chunk pipeline,
// FULL-CHIP OCCUPANCY (256 blocks, 8 rows/block, 32 lanes/row).
//   Round-12 proof: everything issued under the spin is free (even 3.7x HBM
//   traffic); the critical path is publish-visible -> detect -> stage ->
//   compute-after-arrival -> publish. NB=128 left half the CUs idle and
//   the per-CU compute phase read 128 KB LDS (~0.43us) after h arrival.
//   NB=256/TPR=32 halves that to 64 KB (~0.21us) and uses all 256 CUs.
//   Exchange = round-10 best, bit-identical slot layout:
//   - h published as 64-bit {tag = t+1, f32 bits}, relaxed AGENT-scope
//     atomic store (bypasses non-coherent XCD L2); detect IS data arrival.
//   - ring-2 slots; each thread owns 4 words of each half (C0: tid*4,
//     C1: HALF+tid*4); spin on C0 word0; speculative C1 loads under C0
//     verify + compute0; one extra barrier for C1 staging.
//   - W streams from XCD L2 inside compute (compiler-scheduled; R12 showed
//     its placement is off the critical path).
// ---------------------------------------------------------------------------
#define NB   256                 // blocks = CU count (all co-resident)
#define NT   256                 // threads per block
#define RPB  (HID / NB)          // 8 rows per block
#define TPR  32                  // threads (lanes) per row
#define NC   (HID / (TPR * 4))   // 16 float4 chunks per thread-dot
#define HALF (HID / 2)           // 1024: chunk boundary

typedef unsigned long long ull;

__device__ __forceinline__ float fast_tanh(float x) {
  const float e = __expf(2.f * x);
  return 1.f - 2.f / (e + 1.f);
}

__device__ __forceinline__ void pub(ull* p, unsigned tag, float v) {
  const ull w = ((ull)tag << 32) | (ull)__float_as_uint(v);
  __hip_atomic_store(p, w, __ATOMIC_RELAXED, __HIP_MEMORY_SCOPE_AGENT);
}

__device__ __forceinline__ ull ald(const ull* p) {
  return __hip_atomic_load(p, __ATOMIC_RELAXED, __HIP_MEMORY_SCOPE_AGENT);
}

__global__ __launch_bounds__(NT, 1) void esn_recur(const float* __restrict__ W,
                                                   float* __restrict__ out,
                                                   ull* __restrict__ slots) {
  const int tid = threadIdx.x;
  const int j   = tid & (TPR - 1);       // lane within row (0..31)
  const int rl  = tid >> 5;              // local row (0..7)
  const int row = blockIdx.x * RPB + rl;

  __shared__ float hs[2][HID];           // 16 KB: double-buffered h staging

  const float4* wrow = (const float4*)(W + (size_t)row * HID);

  // ---- t = 0: h0 = leak * tanh(P0), publish with tag 1 into ring 0 ----
  float hp = LEAK * fast_tanh(out[row]); // all 32 lanes of a row identical
  if (j == 0) {
    pub(&slots[row], 1u, hp);
    out[row] = hp;
  }

  for (int t = 1; t < T_STEPS; ++t) {
    float* __restrict__ ocur = out + (size_t)t * HID;
    const float p = ocur[row];           // issued early; drains at spin

    const ull* __restrict__ s0 =
        slots + (size_t)((t - 1) & 1) * HID + (size_t)tid * 4;   // C0 words
    const ull* __restrict__ s1 = s0 + HALF;                      // C1 words
    const unsigned tg = (unsigned)t;     // tag of h_{t-1}

    // ---- spin on C0 word 0 (one outstanding poll load) ----
    ull a0;
    do {
      a0 = ald(s0);
    } while ((unsigned)(a0 >> 32) != tg);

    // ---- speculative C1 loads: in flight under C0 verify + compute0 ----
    ull c0 = ald(s1 + 0);
    ull c1 = ald(s1 + 1);
    ull c2 = ald(s1 + 2);
    ull c3 = ald(s1 + 3);

    // ---- verify C0 words 1..3 (usually already current) ----
    ull a1, a2, a3;
    bool ok;
    do {
      a1 = ald(s0 + 1); a2 = ald(s0 + 2); a3 = ald(s0 + 3);
      ok = ((unsigned)(a1 >> 32) == tg) &&
           ((unsigned)(a2 >> 32) == tg) &&
           ((unsigned)(a3 >> 32) == tg);
    } while (!ok);

    float* __restrict__ hb = hs[(t - 1) & 1];
    {
      float4 v;
      v.x = __uint_as_float((unsigned)a0);
      v.y = __uint_as_float((unsigned)a1);
      v.z = __uint_as_float((unsigned)a2);
      v.w = __uint_as_float((unsigned)a3);
      *(float4*)&hb[tid * 4] = v;
    }
    __syncthreads();                     // C0 (h[0..1023]) staged

    // ---- compute chunk 0: i = 0..7 (h[0..1023]) ----
    float4 acc = make_float4(0.f, 0.f, 0.f, 0.f);
#pragma unroll
    for (int i = 0; i < NC / 2; ++i) {
      const int idx = (i * TPR + j) * 4;
      const float4 wv = wrow[i * TPR + j];         // streams from XCD L2
      const float4 hv = *(const float4*)&hb[idx];
      acc.x = fmaf(wv.x, hv.x, acc.x);
      acc.y = fmaf(wv.y, hv.y, acc.y);
      acc.z = fmaf(wv.z, hv.z, acc.z);
      acc.w = fmaf(wv.w, hv.w, acc.w);
    }

    // ---- C1: check speculative values; rare re-poll if stale ----
    while (!(((unsigned)(c0 >> 32) == tg) && ((unsigned)(c1 >> 32) == tg) &&
             ((unsigned)(c2 >> 32) == tg) && ((unsigned)(c3 >> 32) == tg))) {
      c0 = ald(s1 + 0); c1 = ald(s1 + 1);
      c2 = ald(s1 + 2); c3 = ald(s1 + 3);
    }
    {
      float4 v;
      v.x = __uint_as_float((unsigned)c0);
      v.y = __uint_as_float((unsigned)c1);
      v.z = __uint_as_float((unsigned)c2);
      v.w = __uint_as_float((unsigned)c3);
      *(float4*)&hb[HALF + tid * 4] = v;
    }
    __syncthreads();                     // C1 (h[1024..2047]) staged

    // ---- compute chunk 1: i = 8..15 (h[1024..2047]) ----
#pragma unroll
    for (int i = NC / 2; i < NC; ++i) {
      const int idx = (i * TPR + j) * 4;
      const float4 wv = wrow[i * TPR + j];
      const float4 hv = *(const float4*)&hb[idx];
      acc.x = fmaf(wv.x, hv.x, acc.x);
      acc.y = fmaf(wv.y, hv.y, acc.y);
      acc.z = fmaf(wv.z, hv.z, acc.z);
      acc.w = fmaf(wv.w, hv.w, acc.w);
    }
    float a = (acc.x + acc.y) + (acc.z + acc.w);
    a += __shfl_xor(a, 1, TPR);
    a += __shfl_xor(a, 2, TPR);
    a += __shfl_xor(a, 4, TPR);
    a += __shfl_xor(a, 8, TPR);
    a += __shfl_xor(a, 16, TPR);         // all 32 lanes hold the full dot

    const float h = (1.f - LEAK) * hp + LEAK * fast_tanh(p + a);
    hp = h;
    if (j == 0) {
      pub(&slots[(size_t)(t & 1) * HID + row], (unsigned)(t + 1), h);
      ocur[row] = h;                     // plain cached store (own column)
    }
  }
}

// ---------------------------------------------------------------------------
extern "C" void kernel_launch(void* const* d_in, const int* in_sizes, int n_in,
                              void* d_out, int out_size, void* d_ws, size_t ws_size,
                              hipStream_t stream) {
  const float* U    = (const float*)d_in[0];
  const float* Win  = (const float*)d_in[1];
  const float* W    = (const float*)d_in[2];
  const float* bias = (const float*)d_in[3];
  float* out = (float*)d_out;
  ull* slots = (ull*)d_ws;

  // wipe tags (also clears stale tags between graph replays); tag 0 is
  // never a valid tag (tags are t+1 >= 1), so memset can't false-match
  hipMemsetAsync(d_ws, 0, 2 * HID * sizeof(ull), stream);

  dim3 ggrid(T_STEPS / GBM, HID / GBN);
  gemm_p<<<ggrid, 256, 0, stream>>>(U, Win, bias, out);

  esn_recur<<<NB, NT, 0, stream>>>(W, out, slots);
}

// Round 14
// 11468.099 us; speedup vs baseline: 1.2073x; 1.2073x over previous
//
#include <hip/hip_runtime.h>
#include <hip/hip_bf16.h>
#include <math.h>

#define T_STEPS 4096
#define IN_DIM  512
#define HID     2048
#define LEAK    0.3f

// ---------------------------------------------------------------------------
// Phase 1: P = U @ Win^T + bias, written directly into d_out (T x HID, f32)
// ---------------------------------------------------------------------------
#define GBM 64
#define GBN 64
#define GBK 32

__global__ __launch_bounds__(256) void gemm_p(const float* __restrict__ U,
                                              const float* __restrict__ Win,
                                              const float* __restrict__ bias,
                                              float* __restrict__ P) {
  __shared__ float As[GBM][GBK + 1];
  __shared__ float Bs[GBN][GBK + 1];
  const int bm = blockIdx.x, bn = blockIdx.y;
  const int tid = threadIdx.x;
  const int tx = tid & 15, ty = tid >> 4;

  float acc[4][4];
#pragma unroll
  for (int m = 0; m < 4; ++m)
#pragma unroll
    for (int n = 0; n < 4; ++n) acc[m][n] = 0.f;

  const float* Ub = U + (size_t)bm * GBM * IN_DIM;
  const float* Wb = Win + (size_t)bn * GBN * IN_DIM;

  for (int k0 = 0; k0 < IN_DIM; k0 += GBK) {
#pragma unroll
    for (int v = 0; v < 2; ++v) {
      const int f4 = v * 256 + tid;
      const int row = f4 >> 3;
      const int c4 = (f4 & 7) << 2;
      const float4 a = *(const float4*)(Ub + (size_t)row * IN_DIM + k0 + c4);
      As[row][c4 + 0] = a.x; As[row][c4 + 1] = a.y;
      As[row][c4 + 2] = a.z; As[row][c4 + 3] = a.w;
      const float4 b = *(const float4*)(Wb + (size_t)row * IN_DIM + k0 + c4);
      Bs[row][c4 + 0] = b.x; Bs[row][c4 + 1] = b.y;
      Bs[row][c4 + 2] = b.z; Bs[row][c4 + 3] = b.w;
    }
    __syncthreads();
#pragma unroll 8
    for (int k = 0; k < GBK; ++k) {
      float a[4], b[4];
#pragma unroll
      for (int m = 0; m < 4; ++m) a[m] = As[ty * 4 + m][k];
#pragma unroll
      for (int n = 0; n < 4; ++n) b[n] = Bs[tx * 4 + n][k];
#pragma unroll
      for (int m = 0; m < 4; ++m)
#pragma unroll
        for (int n = 0; n < 4; ++n)
          acc[m][n] = fmaf(a[m], b[n], acc[m][n]);
    }
    __syncthreads();
  }

#pragma unroll
  for (int m = 0; m < 4; ++m) {
    const int gr = bm * GBM + ty * 4 + m;
#pragma unroll
    for (int n = 0; n < 4; ++n) {
      const int gc = bn * GBN + tx * 4 + n;
      P[(size_t)gr * HID + gc] = acc[m][n] + bias[gc];
    }
  }
}

// ---------------------------------------------------------------------------
// Phase 2: persistent recurrence, tagged-word exchange, two-chunk pipeline.
// ROUND-10 OPTIMUM, restored. Design-space map (rounds 1-13):
//   step = publish-visible+detect (~2.1us) + stage+compute+tail (~0.65us).
//   - hops are poison: R2 (flag barrier, +2 hops) 10.4us; R5 (sentinels,
//     +2 hops) 5.1us/step; R3 (0 extra hops) 3.25us.
//   - traffic is not the lever: R11 (backoff, traffic/8) null; R6 (4x poll)
//     regress; R12 (3.7x HBM under spin) flat.
//   - fan-in 128 is optimal: NB=64 -> 3.25us, NB=128 -> 2.76us, NB=256 ->
//     3.34us (straggler tail of the completeness condition).
//   - redundancy regresses (R9: 2 groups -> 4.5us/step).
//   - detect-granularity overlap worth only ~3% (R10's C0/C1 pipeline).
//   Protocol: h published as 64-bit {tag = t+1, f32 bits} via relaxed
//   AGENT-scope store (bypasses non-coherent XCD L2; detect IS arrival);
//   ring-2 slots (induction-safe); spin on C0 word0, speculative C1 loads
//   under C0 verify + compute0; double-buffered LDS staging; W streams
//   from XCD L2 inside compute (proven off the critical path).
// ---------------------------------------------------------------------------
#define NB   128                 // blocks (measured fan-in optimum)
#define NT   256                 // threads per block
#define RPB  (HID / NB)          // 16 rows per block
#define TPR  16                  // threads per row
#define NF4  (HID / (TPR * 4))   // 32 float4 chunks per thread-dot
#define HALF (HID / 2)           // 1024: chunk boundary

typedef unsigned long long ull;

__device__ __forceinline__ float fast_tanh(float x) {
  const float e = __expf(2.f * x);
  return 1.f - 2.f / (e + 1.f);
}

__device__ __forceinline__ void pub(ull* p, unsigned tag, float v) {
  const ull w = ((ull)tag << 32) | (ull)__float_as_uint(v);
  __hip_atomic_store(p, w, __ATOMIC_RELAXED, __HIP_MEMORY_SCOPE_AGENT);
}

__device__ __forceinline__ ull ald(const ull* p) {
  return __hip_atomic_load(p, __ATOMIC_RELAXED, __HIP_MEMORY_SCOPE_AGENT);
}

__global__ __launch_bounds__(NT, 1) void esn_recur(const float* __restrict__ W,
                                                   float* __restrict__ out,
                                                   ull* __restrict__ slots) {
  const int tid = threadIdx.x;
  const int j   = tid & (TPR - 1);       // lane within row
  const int rl  = tid >> 4;              // local row (0..15)
  const int row = blockIdx.x * RPB + rl;

  __shared__ float hs[2][HID];           // 16 KB: double-buffered h staging

  const float4* wrow = (const float4*)(W + (size_t)row * HID);

  // ---- t = 0: h0 = leak * tanh(P0), publish with tag 1 into ring 0 ----
  float hp = LEAK * fast_tanh(out[row]); // all 16 lanes of a row identical
  if (j == 0) {
    pub(&slots[row], 1u, hp);
    out[row] = hp;
  }

  for (int t = 1; t < T_STEPS; ++t) {
    float* __restrict__ ocur = out + (size_t)t * HID;
    const float p = ocur[row];           // issued early; drains at barrier 1

    const ull* __restrict__ s0 =
        slots + (size_t)((t - 1) & 1) * HID + (size_t)tid * 4;   // C0 words
    const ull* __restrict__ s1 = s0 + HALF;                      // C1 words
    const unsigned tg = (unsigned)t;     // tag of h_{t-1}

    // ---- spin on C0 word 0 (one outstanding poll load) ----
    ull a0;
    do {
      a0 = ald(s0);
    } while ((unsigned)(a0 >> 32) != tg);

    // ---- speculative C1 loads: in flight under C0 verify + compute0 ----
    ull c0 = ald(s1 + 0);
    ull c1 = ald(s1 + 1);
    ull c2 = ald(s1 + 2);
    ull c3 = ald(s1 + 3);

    // ---- verify C0 words 1..3 ----
    ull a1, a2, a3;
    bool ok;
    do {
      a1 = ald(s0 + 1); a2 = ald(s0 + 2); a3 = ald(s0 + 3);
      ok = ((unsigned)(a1 >> 32) == tg) &&
           ((unsigned)(a2 >> 32) == tg) &&
           ((unsigned)(a3 >> 32) == tg);
    } while (!ok);

    float* __restrict__ hb = hs[(t - 1) & 1];
    {
      float4 v;
      v.x = __uint_as_float((unsigned)a0);
      v.y = __uint_as_float((unsigned)a1);
      v.z = __uint_as_float((unsigned)a2);
      v.w = __uint_as_float((unsigned)a3);
      *(float4*)&hb[tid * 4] = v;
    }
    __syncthreads();                     // C0 staged (drains C1 loads too)

    // ---- compute chunk 0: i = 0..15 (h[0..1023]) ----
    float4 acc = make_float4(0.f, 0.f, 0.f, 0.f);
#pragma unroll
    for (int i = 0; i < NF4 / 2; ++i) {
      const int idx = (i * TPR + j) * 4;
      const float4 wv = wrow[i * TPR + j];
      const float4 hv = *(const float4*)&hb[idx];
      acc.x = fmaf(wv.x, hv.x, acc.x);
      acc.y = fmaf(wv.y, hv.y, acc.y);
      acc.z = fmaf(wv.z, hv.z, acc.z);
      acc.w = fmaf(wv.w, hv.w, acc.w);
    }

    // ---- C1: check speculative values; rare re-poll if stale ----
    while (!(((unsigned)(c0 >> 32) == tg) && ((unsigned)(c1 >> 32) == tg) &&
             ((unsigned)(c2 >> 32) == tg) && ((unsigned)(c3 >> 32) == tg))) {
      c0 = ald(s1 + 0); c1 = ald(s1 + 1);
      c2 = ald(s1 + 2); c3 = ald(s1 + 3);
    }
    {
      float4 v;
      v.x = __uint_as_float((unsigned)c0);
      v.y = __uint_as_float((unsigned)c1);
      v.z = __uint_as_float((unsigned)c2);
      v.w = __uint_as_float((unsigned)c3);
      *(float4*)&hb[HALF + tid * 4] = v;
    }
    __syncthreads();                     // C1 staged

    // ---- compute chunk 1: i = 16..31 (h[1024..2047]) ----
#pragma unroll
    for (int i = NF4 / 2; i < NF4; ++i) {
      const int idx = (i * TPR + j) * 4;
      const float4 wv = wrow[i * TPR + j];
      const float4 hv = *(const float4*)&hb[idx];
      acc.x = fmaf(wv.x, hv.x, acc.x);
      acc.y = fmaf(wv.y, hv.y, acc.y);
      acc.z = fmaf(wv.z, hv.z, acc.z);
      acc.w = fmaf(wv.w, hv.w, acc.w);
    }
    float a = (acc.x + acc.y) + (acc.z + acc.w);
    a += __shfl_xor(a, 1, TPR);
    a += __shfl_xor(a, 2, TPR);
    a += __shfl_xor(a, 4, TPR);
    a += __shfl_xor(a, 8, TPR);          // all 16 lanes hold the full dot

    const float h = (1.f - LEAK) * hp + LEAK * fast_tanh(p + a);
    hp = h;
    if (j == 0) {
      pub(&slots[(size_t)(t & 1) * HID + row], (unsigned)(t + 1), h);
      ocur[row] = h;                     // plain cached store (own column)
    }
  }
}

// ---------------------------------------------------------------------------
extern "C" void kernel_launch(void* const* d_in, const int* in_sizes, int n_in,
                              void* d_out, int out_size, void* d_ws, size_t ws_size,
                              hipStream_t stream) {
  const float* U    = (const float*)d_in[0];
  const float* Win  = (const float*)d_in[1];
  const float* W    = (const float*)d_in[2];
  const float* bias = (const float*)d_in[3];
  float* out = (float*)d_out;
  ull* slots = (ull*)d_ws;

  // wipe tags (also clears stale tags between graph replays); tag 0 is
  // never a valid tag (tags are t+1 >= 1), so memset can't false-match
  hipMemsetAsync(d_ws, 0, 2 * HID * sizeof(ull), stream);

  dim3 ggrid(T_STEPS / GBM, HID / GBN);
  gemm_p<<<ggrid, 256, 0, stream>>>(U, Win, bias, out);

  esn_recur<<<NB, NT, 0, stream>>>(W, out, slots);
}